// Round 4
// baseline (295.981 us; speedup 1.0000x reference)
//
#include <hip/hip_runtime.h>
#include <hip/hip_bf16.h>
#include <type_traits>

// Problem: B=2, T=2048, D_MODEL=2048, H=16, Hkv=4, hd=128.
// Outputs (fp32, concat): out[2,2048,2048] | k_roped[2,4,2048,128] | v[2,4,2048,128]

typedef short  short8 __attribute__((ext_vector_type(8)));
typedef float  f32x4  __attribute__((ext_vector_type(4)));

#define AS1(p) ((__attribute__((address_space(1))) void*)(p))
#define AS3(p) ((__attribute__((address_space(3))) void*)(p))

static __device__ inline short bf_bits(float f) {
    __hip_bfloat16 h = __float2bfloat16(f);
    return *reinterpret_cast<short*>(&h);
}

// ---------------- x fp32 -> bf16 ----------------
__global__ __launch_bounds__(256) void convert_x_kernel(
    const float* __restrict__ x, __hip_bfloat16* __restrict__ xb)
{
    int i = (blockIdx.x * 256 + threadIdx.x) * 4;
    float4 v = *reinterpret_cast<const float4*>(x + i);
    ushort4 o;
    o.x = (unsigned short)bf_bits(v.x);
    o.y = (unsigned short)bf_bits(v.y);
    o.z = (unsigned short)bf_bits(v.z);
    o.w = (unsigned short)bf_bits(v.w);
    *reinterpret_cast<ushort4*>(reinterpret_cast<unsigned short*>(xb) + i) = o;
}

// ---------------- W [K][N] fp32 -> WT [N][K] bf16 ----------------
__global__ void transpose_convert_kernel(
    const float* __restrict__ W, __hip_bfloat16* __restrict__ WT, int K, int N)
{
    __shared__ float tile[32][33];
    int n0 = blockIdx.x * 32, k0 = blockIdx.y * 32;
    int tx = threadIdx.x, ty = threadIdx.y;   // 32 x 8
#pragma unroll
    for (int i = 0; i < 32; i += 8)
        tile[ty + i][tx] = W[(size_t)(k0 + ty + i) * N + n0 + tx];
    __syncthreads();
#pragma unroll
    for (int i = 0; i < 32; i += 8)
        WT[(size_t)(n0 + ty + i) * K + k0 + tx] = __float2bfloat16(tile[tx][ty + i]);
}

// ---------------- GEMM: C[M][N] = A[M][K] * BT[N][K]^T (bf16 in, f32 acc) ----------------
template <typename CT>
__global__ __launch_bounds__(256) void gemm_bt_kernel(
    const __hip_bfloat16* __restrict__ A,
    const __hip_bfloat16* __restrict__ BT,
    CT* __restrict__ C, int M, int N, int K)
{
    const int tid  = threadIdx.x;
    const int w    = tid >> 6;
    const int lane = tid & 63;
    const int lo16 = lane & 15;
    const int grp  = lane >> 4;
    const int m0 = blockIdx.y << 7;
    const int n0 = blockIdx.x << 7;
    const int wm = (w >> 1) << 6;
    const int wn = (w & 1) << 6;

    __shared__ __hip_bfloat16 As[128 * 32];
    __shared__ __hip_bfloat16 Bs[128 * 32];

    f32x4 acc[4][4] = {};

    const int ch0 = w * 128 + lane;
    const int ch1 = ch0 + 64;

    for (int k0 = 0; k0 < K; k0 += 32) {
        {
            const __hip_bfloat16* ga0 = A + (size_t)(m0 + (ch0 >> 2)) * K + k0 + (ch0 & 3) * 8;
            const __hip_bfloat16* ga1 = A + (size_t)(m0 + (ch1 >> 2)) * K + k0 + (ch1 & 3) * 8;
            const __hip_bfloat16* gb0 = BT + (size_t)(n0 + (ch0 >> 2)) * K + k0 + (ch0 & 3) * 8;
            const __hip_bfloat16* gb1 = BT + (size_t)(n0 + (ch1 >> 2)) * K + k0 + (ch1 & 3) * 8;
            __builtin_amdgcn_global_load_lds(AS1(ga0), AS3(As + w * 1024),       16, 0, 0);
            __builtin_amdgcn_global_load_lds(AS1(ga1), AS3(As + w * 1024 + 512), 16, 0, 0);
            __builtin_amdgcn_global_load_lds(AS1(gb0), AS3(Bs + w * 1024),       16, 0, 0);
            __builtin_amdgcn_global_load_lds(AS1(gb1), AS3(Bs + w * 1024 + 512), 16, 0, 0);
        }
        __syncthreads();

        short8 af[4], bf[4];
#pragma unroll
        for (int mi = 0; mi < 4; ++mi)
            af[mi] = *reinterpret_cast<const short8*>(
                reinterpret_cast<const short*>(As) + (wm + mi * 16 + lo16) * 32 + grp * 8);
#pragma unroll
        for (int ni = 0; ni < 4; ++ni)
            bf[ni] = *reinterpret_cast<const short8*>(
                reinterpret_cast<const short*>(Bs) + (wn + ni * 16 + lo16) * 32 + grp * 8);
#pragma unroll
        for (int mi = 0; mi < 4; ++mi)
#pragma unroll
            for (int ni = 0; ni < 4; ++ni)
                acc[mi][ni] = __builtin_amdgcn_mfma_f32_16x16x32_bf16(
                    af[mi], bf[ni], acc[mi][ni], 0, 0, 0);
        __syncthreads();
    }

#pragma unroll
    for (int mi = 0; mi < 4; ++mi)
#pragma unroll
        for (int ni = 0; ni < 4; ++ni)
#pragma unroll
            for (int r = 0; r < 4; ++r) {
                int row = m0 + wm + mi * 16 + grp * 4 + r;
                int col = n0 + wn + ni * 16 + lo16;
                float v = acc[mi][ni][r];
                if constexpr (std::is_same<CT, float>::value)
                    C[(size_t)row * N + col] = v;
                else
                    C[(size_t)row * N + col] = __float2bfloat16(v);
            }
}

// ---------------- RoPE on Q (16 heads) and K (4 heads) in qkv, k->d_out ----------------
__global__ __launch_bounds__(256) void rope_qk_kernel(
    __hip_bfloat16* __restrict__ qkv, float* __restrict__ outk)
{
    int idx = blockIdx.x * 256 + threadIdx.x;   // 4096*20*64
    int row = idx / 1280;
    int rem = idx - row * 1280;
    int hh = rem >> 6, d = rem & 63;
    int b = row >> 11, t = row & 2047;
    int col = (hh < 16) ? hh * 128 + d : 2048 + (hh - 16) * 128 + d;
    __hip_bfloat16* p = qkv + (size_t)row * 3072 + col;
    float x1 = __bfloat162float(p[0]);
    float x2 = __bfloat162float(p[64]);
    float invf = exp2f((float)d * -0.20762050593046f);  // 10000^(-d/64)
    float ang = (float)t * invf;
    float s, c;
    sincosf(ang, &s, &c);
    float o1 = x1 * c - x2 * s;
    float o2 = x2 * c + x1 * s;
    p[0]  = __float2bfloat16(o1);
    p[64] = __float2bfloat16(o2);
    if (hh >= 16) {
        int kh = hh - 16;
        float* ok = outk + (size_t)((b * 4 + kh) * 2048 + t) * 128 + d;
        ok[0]  = o1;
        ok[64] = o2;
    }
}

// ---------------- V: fp32 to d_out + bf16 V^T for attention ----------------
__global__ __launch_bounds__(256) void v_writeout_kernel(
    const __hip_bfloat16* __restrict__ qkv, float* __restrict__ outv,
    __hip_bfloat16* __restrict__ VT)
{
    int idx = blockIdx.x * 256 + threadIdx.x;   // 2^21: [b][kh][t][d]
    int d  = idx & 127;
    int t  = (idx >> 7) & 2047;
    int kh = (idx >> 18) & 3;
    int b  = idx >> 20;
    __hip_bfloat16 v = qkv[(size_t)(b * 2048 + t) * 3072 + 2560 + kh * 128 + d];
    outv[idx] = __bfloat162float(v);
    VT[(size_t)((b * 4 + kh) * 128 + d) * 2048 + t] = v;
}

// ---------------- Flash attention v4 (causal, GQA) ----------------
// 128 threads = 2 waves, each wave owns 32 q-rows (q-block = 64). KVBLK = 64.
// Single-buffered K/V in LDS (40 KB total incl. per-wave P) -> 4 blocks/CU
// co-resident (whole 1024-block grid resident); stall hiding via inter-block
// TLP instead of intra-block double buffering. XCD-aware bid decode: each XCD
// serves 4 heads (4 MB K/V = one L2); each CU's 4 blocks sum to exactly 66
// tiles (u / 31-u pairing) -> no makespan tail.
__global__ __launch_bounds__(128, 2) void attn_kernel(
    const __hip_bfloat16* __restrict__ qkv,
    const __hip_bfloat16* __restrict__ VT,
    __hip_bfloat16* __restrict__ outO)
{
    // ---- bid decode: XCD-local heads, balanced qq mix per CU
    const int o_ = blockIdx.x;          // 0..1023
    const int xcd = o_ & 7;
    const int r_ = o_ >> 3;             // 0..127
    const int u = r_ & 31;              // CU-slot index within XCD
    const int j = r_ >> 5;              // 0..3: head index within XCD
    const int bh = xcd * 4 + j;         // b*16 + h
    int qq;                             // q-block index 0..31, tiles = qq+1
    switch (j) {
        case 0:  qq = u; break;
        case 1:  qq = 31 - u; break;
        case 2:  qq = (u + 16) & 31; break;
        default: qq = (15 - u) & 31; break;
    }
    const int b = bh >> 4, h = bh & 15;
    const int kh = h >> 2;
    const int tid = threadIdx.x;
    const int w = tid >> 6;
    const int lane = tid & 63;
    const int lo16 = lane & 15, grp = lane >> 4;
    const int qrow0 = qq * 64 + w * 32;

    __shared__ short Ks[64 * 128];      // 16 KB  [key][d]   (swizzled octets)
    __shared__ short Vs[128 * 64];      // 16 KB  [d][key]   (swizzled octets)
    __shared__ short Ps[2][32 * 64];    //  8 KB  per-wave P (swizzled octets)

    const short* qkvs = reinterpret_cast<const short*>(qkv);
    const size_t kbase = (size_t)b * 2048 * 3072 + 2048 + kh * 128;
    const short* vtb = reinterpret_cast<const short*>(VT) + (size_t)(b * 4 + kh) * 128 * 2048;
    short* pw = &Ps[w][0];

    // Q fragments: rows qrow0 + mi*16 + lo16, k-slice ss*32 + grp*8
    short8 qf[2][4];
#pragma unroll
    for (int mi = 0; mi < 2; ++mi) {
        const short* qp = qkvs + (size_t)(b * 2048 + qrow0 + mi * 16 + lo16) * 3072
                        + h * 128 + grp * 8;
#pragma unroll
        for (int ss = 0; ss < 4; ++ss)
            qf[mi][ss] = *reinterpret_cast<const short8*>(qp + ss * 32);
    }

    f32x4 o[2][8] = {};
    f32x4 lac[2] = {};
    float m[8];
#pragma unroll
    for (int r = 0; r < 8; ++r) m[r] = -1e30f;

    short8 ones;
#pragma unroll
    for (int jj = 0; jj < 8; ++jj) ones[jj] = (short)0x3F80;   // bf16 1.0

    const float scl2 = 0.12752749545902973f;   // (1/sqrt(128)) * log2(e)
    const int ntiles = qq + 1;

    // K octets: c = tid + i*128 (1024 total): row=c>>4, src col16=(c&15)^(row&7)
    // V octets: d = c>>3, src col8 = (c&7)^(d&7)
#define STAGE(kb_)                                                                   \
    {                                                                                \
        _Pragma("unroll")                                                            \
        for (int i = 0; i < 8; ++i) {                                                \
            int c = tid + i * 128;                                                   \
            int row = c >> 4, c16 = (c & 15) ^ (row & 7);                            \
            const short* src = qkvs + kbase + (size_t)((kb_) + row) * 3072 + c16 * 8;\
            __builtin_amdgcn_global_load_lds(AS1(src),                               \
                AS3(&Ks[(w * 64 + i * 128) * 8]), 16, 0, 0);                         \
        }                                                                            \
        _Pragma("unroll")                                                            \
        for (int i = 0; i < 8; ++i) {                                                \
            int c = tid + i * 128;                                                   \
            int d = c >> 3, c8 = (c & 7) ^ (d & 7);                                  \
            const short* src = vtb + (size_t)d * 2048 + (kb_) + c8 * 8;              \
            __builtin_amdgcn_global_load_lds(AS1(src),                               \
                AS3(&Vs[(w * 64 + i * 128) * 8]), 16, 0, 0);                         \
        }                                                                            \
    }

    STAGE(0);
    __syncthreads();

    for (int t = 0; t < ntiles; ++t) {
        const int kb = t * 64;

        // ---- QK^T: S[mi][q=grp*4+r][key=kg*16+lo16], K-frag shared across mi
        f32x4 sg[2][4];
        __builtin_amdgcn_s_setprio(1);
#pragma unroll
        for (int kg = 0; kg < 4; ++kg) {
            f32x4 a0 = {}, a1 = {};
#pragma unroll
            for (int ss = 0; ss < 4; ++ss) {
                short8 kf = *reinterpret_cast<const short8*>(
                    &Ks[(kg * 16 + lo16) * 128 + (((ss * 4 + grp) ^ (lo16 & 7)) << 3)]);
                a0 = __builtin_amdgcn_mfma_f32_16x16x32_bf16(qf[0][ss], kf, a0, 0, 0, 0);
                a1 = __builtin_amdgcn_mfma_f32_16x16x32_bf16(qf[1][ss], kf, a1, 0, 0, 0);
            }
            sg[0][kg] = a0; sg[1][kg] = a1;
        }
        __builtin_amdgcn_s_setprio(0);

        // ---- scale (log2 domain) + causal mask (only near diagonal)
        if (kb + 63 > qrow0) {
#pragma unroll
            for (int mi = 0; mi < 2; ++mi)
#pragma unroll
                for (int kg = 0; kg < 4; ++kg) {
                    const int key = kb + kg * 16 + lo16;
#pragma unroll
                    for (int r = 0; r < 4; ++r) {
                        float v = sg[mi][kg][r] * scl2;
                        sg[mi][kg][r] = (key <= qrow0 + mi * 16 + grp * 4 + r) ? v : -1e30f;
                    }
                }
        } else {
#pragma unroll
            for (int mi = 0; mi < 2; ++mi)
#pragma unroll
                for (int kg = 0; kg < 4; ++kg)
#pragma unroll
                    for (int r = 0; r < 4; ++r) sg[mi][kg][r] *= scl2;
        }

        // ---- row max over 64 keys: 4-way local + 16-lane butterfly
        float pm[8];
#pragma unroll
        for (int mi = 0; mi < 2; ++mi)
#pragma unroll
            for (int r = 0; r < 4; ++r)
                pm[mi * 4 + r] = fmaxf(fmaxf(sg[mi][0][r], sg[mi][1][r]),
                                       fmaxf(sg[mi][2][r], sg[mi][3][r]));
#pragma unroll
        for (int off = 1; off < 16; off <<= 1)
#pragma unroll
            for (int i = 0; i < 8; ++i) pm[i] = fmaxf(pm[i], __shfl_xor(pm[i], off));

        // ---- defer-max: rescale only when max grew materially (log2 dom, THR=11.5)
        bool ok = true;
#pragma unroll
        for (int i = 0; i < 8; ++i) ok = ok && (pm[i] <= m[i] + 11.5f);
        if (!__all(ok)) {
            float c[8];
#pragma unroll
            for (int i = 0; i < 8; ++i) {
                float mn = fmaxf(m[i], pm[i]);
                c[i] = __builtin_amdgcn_exp2f(m[i] - mn);
                m[i] = mn;
            }
#pragma unroll
            for (int mi = 0; mi < 2; ++mi) {
#pragma unroll
                for (int jj = 0; jj < 8; ++jj)
#pragma unroll
                    for (int r = 0; r < 4; ++r) o[mi][jj][r] *= c[mi * 4 + r];
#pragma unroll
                for (int r = 0; r < 4; ++r) lac[mi][r] *= c[mi * 4 + r];
            }
        }

        // ---- exp2 + P store (swizzled): row = mi*16 + grp*4 + r, col = kg*16+lo16
#pragma unroll
        for (int mi = 0; mi < 2; ++mi)
#pragma unroll
            for (int kg = 0; kg < 4; ++kg)
#pragma unroll
                for (int r = 0; r < 4; ++r) {
                    float p = __builtin_amdgcn_exp2f(sg[mi][kg][r] - m[mi * 4 + r]);
                    int row = mi * 16 + grp * 4 + r;
                    int idx = row * 64 + (((kg * 2 + (lo16 >> 3)) ^ (row & 7)) << 3) + (lo16 & 7);
                    pw[idx] = bf_bits(p);
                }

        // ---- PV + row-sum: V-frag shared across mi; l via ones-MFMA
        __builtin_amdgcn_s_setprio(1);
#pragma unroll
        for (int ks = 0; ks < 2; ++ks) {
            short8 pf0 = *reinterpret_cast<const short8*>(
                &pw[(0 * 16 + lo16) * 64 + (((ks * 4 + grp) ^ (lo16 & 7)) << 3)]);
            short8 pf1 = *reinterpret_cast<const short8*>(
                &pw[(1 * 16 + lo16) * 64 + (((ks * 4 + grp) ^ (lo16 & 7)) << 3)]);
            lac[0] = __builtin_amdgcn_mfma_f32_16x16x32_bf16(pf0, ones, lac[0], 0, 0, 0);
            lac[1] = __builtin_amdgcn_mfma_f32_16x16x32_bf16(pf1, ones, lac[1], 0, 0, 0);
#pragma unroll
            for (int jj = 0; jj < 8; ++jj) {
                short8 vf = *reinterpret_cast<const short8*>(
                    &Vs[(jj * 16 + lo16) * 64 + (((ks * 4 + grp) ^ (lo16 & 7)) << 3)]);
                o[0][jj] = __builtin_amdgcn_mfma_f32_16x16x32_bf16(pf0, vf, o[0][jj], 0, 0, 0);
                o[1][jj] = __builtin_amdgcn_mfma_f32_16x16x32_bf16(pf1, vf, o[1][jj], 0, 0, 0);
            }
        }
        __builtin_amdgcn_s_setprio(0);

        __syncthreads();                       // all waves done reading K/V
        if (t + 1 < ntiles) {
            STAGE(kb + 64);
            __syncthreads();                   // vmcnt drained -> new tile visible
        }
    }
#undef STAGE

#pragma unroll
    for (int mi = 0; mi < 2; ++mi)
#pragma unroll
        for (int r = 0; r < 4; ++r) {
            float inv = 1.0f / lac[mi][r];
#pragma unroll
            for (int jj = 0; jj < 8; ++jj) {
                outO[(size_t)(b * 2048 + qrow0 + mi * 16 + grp * 4 + r) * 2048
                     + h * 128 + jj * 16 + lo16] = __float2bfloat16(o[mi][jj][r] * inv);
            }
        }
}

extern "C" void kernel_launch(void* const* d_in, const int* in_sizes, int n_in,
                              void* d_out, int out_size, void* d_ws, size_t ws_size,
                              hipStream_t stream)
{
    (void)in_sizes; (void)n_in; (void)out_size; (void)ws_size;
    const float* x  = (const float*)d_in[0];
    const float* Wq = (const float*)d_in[1];
    const float* Wk = (const float*)d_in[2];
    const float* Wv = (const float*)d_in[3];
    const float* Wo = (const float*)d_in[4];

    float* out0 = (float*)d_out;                  // [2,2048,2048]
    float* outk = out0 + 8388608;                 // [2,4,2048,128]
    float* outv = out0 + 10485760;                // [2,4,2048,128]

    __hip_bfloat16* wsb    = (__hip_bfloat16*)d_ws;
    __hip_bfloat16* xb     = wsb;                   //  8,388,608  [4096][2048]
    __hip_bfloat16* WqkvT  = xb + 8388608;          //  6,291,456  [3072][2048]
    __hip_bfloat16* WoT    = WqkvT + 6291456;       //  4,194,304  [2048][2048]
    __hip_bfloat16* qkv    = WoT + 4194304;         // 12,582,912  [4096][3072]
    __hip_bfloat16* VT     = qkv + 12582912;        //  2,097,152  [8][128][2048]
    __hip_bfloat16* attn_o = xb;                    // alias: xb dead after QKV GEMM

    convert_x_kernel<<<8192, 256, 0, stream>>>(x, xb);
    transpose_convert_kernel<<<dim3(64, 64), dim3(32, 8), 0, stream>>>(Wq, WqkvT, 2048, 2048);
    transpose_convert_kernel<<<dim3(16, 64), dim3(32, 8), 0, stream>>>(Wk, WqkvT + (size_t)2048 * 2048, 2048, 512);
    transpose_convert_kernel<<<dim3(16, 64), dim3(32, 8), 0, stream>>>(Wv, WqkvT + (size_t)2560 * 2048, 2048, 512);
    transpose_convert_kernel<<<dim3(64, 64), dim3(32, 8), 0, stream>>>(Wo, WoT, 2048, 2048);

    gemm_bt_kernel<__hip_bfloat16><<<dim3(24, 32), 256, 0, stream>>>(xb, WqkvT, qkv, 4096, 3072, 2048);

    rope_qk_kernel<<<20480, 256, 0, stream>>>(qkv, outk);
    v_writeout_kernel<<<8192, 256, 0, stream>>>(qkv, outv, VT);

    attn_kernel<<<1024, 128, 0, stream>>>(qkv, VT, attn_o);

    gemm_bt_kernel<float><<<dim3(16, 32), 256, 0, stream>>>(attn_o, WoT, out0, 4096, 2048, 2048);
}

// Round 5
// 249.907 us; speedup vs baseline: 1.1844x; 1.1844x over previous
//
#include <hip/hip_runtime.h>
#include <hip/hip_bf16.h>
#include <type_traits>

// Problem: B=2, T=2048, D_MODEL=2048, H=16, Hkv=4, hd=128.
// Outputs (fp32, concat): out[2,2048,2048] | k_roped[2,4,2048,128] | v[2,4,2048,128]

typedef short  short8 __attribute__((ext_vector_type(8)));
typedef float  f32x4  __attribute__((ext_vector_type(4)));

#define AS1(p) ((__attribute__((address_space(1))) void*)(p))
#define AS3(p) ((__attribute__((address_space(3))) void*)(p))

static __device__ inline short bf_bits(float f) {
    __hip_bfloat16 h = __float2bfloat16(f);
    return *reinterpret_cast<short*>(&h);
}

// ---------------- x fp32 -> bf16 ----------------
__global__ __launch_bounds__(256) void convert_x_kernel(
    const float* __restrict__ x, __hip_bfloat16* __restrict__ xb)
{
    int i = (blockIdx.x * 256 + threadIdx.x) * 4;
    float4 v = *reinterpret_cast<const float4*>(x + i);
    ushort4 o;
    o.x = (unsigned short)bf_bits(v.x);
    o.y = (unsigned short)bf_bits(v.y);
    o.z = (unsigned short)bf_bits(v.z);
    o.w = (unsigned short)bf_bits(v.w);
    *reinterpret_cast<ushort4*>(reinterpret_cast<unsigned short*>(xb) + i) = o;
}

// ---------------- W [K][N] fp32 -> WT [N][K] bf16 ----------------
__global__ void transpose_convert_kernel(
    const float* __restrict__ W, __hip_bfloat16* __restrict__ WT, int K, int N)
{
    __shared__ float tile[32][33];
    int n0 = blockIdx.x * 32, k0 = blockIdx.y * 32;
    int tx = threadIdx.x, ty = threadIdx.y;   // 32 x 8
#pragma unroll
    for (int i = 0; i < 32; i += 8)
        tile[ty + i][tx] = W[(size_t)(k0 + ty + i) * N + n0 + tx];
    __syncthreads();
#pragma unroll
    for (int i = 0; i < 32; i += 8)
        WT[(size_t)(n0 + ty + i) * K + k0 + tx] = __float2bfloat16(tile[tx][ty + i]);
}

// ---------------- GEMM: C[M][N] = A[M][K] * BT[N][K]^T (bf16 in, f32 acc) ----------------
// 128x128 tile, 4 waves, BK=64 (one barrier pair per 64 K), XOR-swizzled
// staging: global source octet pre-swizzled (oct ^= row&7), LDS dest linear,
// frag reads apply the same XOR -> bank-optimal ds_read_b128.
template <typename CT>
__global__ __launch_bounds__(256) void gemm_bt_kernel(
    const __hip_bfloat16* __restrict__ A,
    const __hip_bfloat16* __restrict__ BT,
    CT* __restrict__ C, int M, int N, int K)
{
    const int tid  = threadIdx.x;
    const int w    = tid >> 6;
    const int lane = tid & 63;
    const int lo16 = lane & 15;
    const int grp  = lane >> 4;
    const int m0 = blockIdx.y << 7;
    const int n0 = blockIdx.x << 7;
    const int wm = (w >> 1) << 6;
    const int wn = (w & 1) << 6;

    __shared__ __hip_bfloat16 As[128 * 64];   // 16 KB
    __shared__ __hip_bfloat16 Bs[128 * 64];   // 16 KB

    f32x4 acc[4][4] = {};

    for (int k0 = 0; k0 < K; k0 += 64) {
#pragma unroll
        for (int i = 0; i < 4; ++i) {
            int c = tid + i * 256;            // octet id 0..1023: row=c>>3, oct=c&7
            int row = c >> 3;
            int soct = (c & 7) ^ (row & 7);   // pre-swizzled source octet
            const __hip_bfloat16* ga = A  + (size_t)(m0 + row) * K + k0 + soct * 8;
            const __hip_bfloat16* gb = BT + (size_t)(n0 + row) * K + k0 + soct * 8;
            __builtin_amdgcn_global_load_lds(AS1(ga), AS3(As + c * 8), 16, 0, 0);
            __builtin_amdgcn_global_load_lds(AS1(gb), AS3(Bs + c * 8), 16, 0, 0);
        }
        __syncthreads();

        short8 af[2][4], bf[2][4];
#pragma unroll
        for (int kk = 0; kk < 2; ++kk) {
#pragma unroll
            for (int mi = 0; mi < 4; ++mi)
                af[kk][mi] = *reinterpret_cast<const short8*>(
                    reinterpret_cast<const short*>(As)
                    + (wm + mi * 16 + lo16) * 64 + (((kk * 4 + grp) ^ (lo16 & 7)) << 3));
#pragma unroll
            for (int ni = 0; ni < 4; ++ni)
                bf[kk][ni] = *reinterpret_cast<const short8*>(
                    reinterpret_cast<const short*>(Bs)
                    + (wn + ni * 16 + lo16) * 64 + (((kk * 4 + grp) ^ (lo16 & 7)) << 3));
        }
#pragma unroll
        for (int mi = 0; mi < 4; ++mi)
#pragma unroll
            for (int ni = 0; ni < 4; ++ni) {
                acc[mi][ni] = __builtin_amdgcn_mfma_f32_16x16x32_bf16(
                    af[0][mi], bf[0][ni], acc[mi][ni], 0, 0, 0);
                acc[mi][ni] = __builtin_amdgcn_mfma_f32_16x16x32_bf16(
                    af[1][mi], bf[1][ni], acc[mi][ni], 0, 0, 0);
            }
        __syncthreads();
    }

#pragma unroll
    for (int mi = 0; mi < 4; ++mi)
#pragma unroll
        for (int ni = 0; ni < 4; ++ni)
#pragma unroll
            for (int r = 0; r < 4; ++r) {
                int row = m0 + wm + mi * 16 + grp * 4 + r;
                int col = n0 + wn + ni * 16 + lo16;
                float v = acc[mi][ni][r];
                if constexpr (std::is_same<CT, float>::value)
                    C[(size_t)row * N + col] = v;
                else
                    C[(size_t)row * N + col] = __float2bfloat16(v);
            }
}

// ---------------- RoPE on Q (16 heads) and K (4 heads) in qkv, k->d_out ----------------
__global__ __launch_bounds__(256) void rope_qk_kernel(
    __hip_bfloat16* __restrict__ qkv, float* __restrict__ outk)
{
    int idx = blockIdx.x * 256 + threadIdx.x;   // 4096*20*64
    int row = idx / 1280;
    int rem = idx - row * 1280;
    int hh = rem >> 6, d = rem & 63;
    int b = row >> 11, t = row & 2047;
    int col = (hh < 16) ? hh * 128 + d : 2048 + (hh - 16) * 128 + d;
    __hip_bfloat16* p = qkv + (size_t)row * 3072 + col;
    float x1 = __bfloat162float(p[0]);
    float x2 = __bfloat162float(p[64]);
    float invf = exp2f((float)d * -0.20762050593046f);  // 10000^(-d/64)
    float ang = (float)t * invf;
    float s, c;
    sincosf(ang, &s, &c);
    float o1 = x1 * c - x2 * s;
    float o2 = x2 * c + x1 * s;
    p[0]  = __float2bfloat16(o1);
    p[64] = __float2bfloat16(o2);
    if (hh >= 16) {
        int kh = hh - 16;
        float* ok = outk + (size_t)((b * 4 + kh) * 2048 + t) * 128 + d;
        ok[0]  = o1;
        ok[64] = o2;
    }
}

// ---------------- V: fp32 to d_out + bf16 V^T for attention ----------------
__global__ __launch_bounds__(256) void v_writeout_kernel(
    const __hip_bfloat16* __restrict__ qkv, float* __restrict__ outv,
    __hip_bfloat16* __restrict__ VT)
{
    int idx = blockIdx.x * 256 + threadIdx.x;   // 2^21: [b][kh][t][d]
    int d  = idx & 127;
    int t  = (idx >> 7) & 2047;
    int kh = (idx >> 18) & 3;
    int b  = idx >> 20;
    __hip_bfloat16 v = qkv[(size_t)(b * 2048 + t) * 3072 + 2560 + kh * 128 + d];
    outv[idx] = __bfloat162float(v);
    VT[(size_t)((b * 4 + kh) * 128 + d) * 2048 + t] = v;
}

// ---------------- Flash attention v5 (causal, GQA) ----------------
// = v3 structure (best so far: 4 waves x 32 q-rows, KVBLK=64, double-buffered
// K/V via global_load_lds, swizzled) with LDS cut 80->72 KB so TWO blocks/CU
// are genuinely co-resident (2x72=144 < 160 KiB; v3's 2x80=160 exact fit
// failed to co-schedule -> 13.6% occupancy). P buffer halved to [16][64]
// per wave; PV runs as two mi-passes (P store->read is same-wave in-order,
// no barrier needed; V frags read twice - cheap vs latency win).
__global__ __launch_bounds__(256, 2) void attn_kernel(
    const __hip_bfloat16* __restrict__ qkv,
    const __hip_bfloat16* __restrict__ VT,
    __hip_bfloat16* __restrict__ outO)
{
    const int bh = blockIdx.x;          // b*16 + h
    const int b = bh >> 4, h = bh & 15;
    const int kh = h >> 2;
    const int yb = blockIdx.y;          // 0..15
    const int qblk = (yb < 8) ? (15 - yb) : (yb - 8);   // LPT: heavy blocks first
    const int tid = threadIdx.x;
    const int w = tid >> 6;
    const int lane = tid & 63;
    const int lo16 = lane & 15, grp = lane >> 4;
    const int qrow0 = qblk * 128 + w * 32;

    __shared__ short Ks[2][64 * 128];   // 32 KB  [key][d]   (swizzled octets)
    __shared__ short Vs[2][128 * 64];   // 32 KB  [d][key]   (swizzled octets)
    __shared__ short Ps[4][16 * 64];    //  8 KB  per-wave P half (swizzled octets)

    const short* qkvs = reinterpret_cast<const short*>(qkv);
    const size_t kbase = (size_t)b * 2048 * 3072 + 2048 + kh * 128;
    const short* vtb = reinterpret_cast<const short*>(VT) + (size_t)(b * 4 + kh) * 128 * 2048;
    short* pw = &Ps[w][0];

    // Q fragments: rows qrow0 + mi*16 + lo16, k-slice ss*32 + grp*8
    short8 qf[2][4];
#pragma unroll
    for (int mi = 0; mi < 2; ++mi) {
        const short* qp = qkvs + (size_t)(b * 2048 + qrow0 + mi * 16 + lo16) * 3072
                        + h * 128 + grp * 8;
#pragma unroll
        for (int ss = 0; ss < 4; ++ss)
            qf[mi][ss] = *reinterpret_cast<const short8*>(qp + ss * 32);
    }

    f32x4 o[2][8] = {};
    f32x4 lac[2] = {};
    float m[8];
#pragma unroll
    for (int r = 0; r < 8; ++r) m[r] = -1e30f;

    short8 ones;
#pragma unroll
    for (int jj = 0; jj < 8; ++jj) ones[jj] = (short)0x3F80;   // bf16 1.0

    const float scl2 = 0.12752749545902973f;   // (1/sqrt(128)) * log2(e)
    const int ntiles = qblk * 2 + 2;

#define STAGE(buf, kb_)                                                              \
    {                                                                                \
        _Pragma("unroll")                                                            \
        for (int i = 0; i < 4; ++i) {                                                \
            int c = tid + i * 256;                                                   \
            int row = c >> 4, c16 = (c & 15) ^ (row & 7);                            \
            const short* src = qkvs + kbase + (size_t)((kb_) + row) * 3072 + c16 * 8;\
            __builtin_amdgcn_global_load_lds(AS1(src),                               \
                AS3(&Ks[buf][(w * 64 + i * 256) * 8]), 16, 0, 0);                    \
        }                                                                            \
        _Pragma("unroll")                                                            \
        for (int i = 0; i < 4; ++i) {                                                \
            int c = tid + i * 256;                                                   \
            int d = c >> 3, c8 = (c & 7) ^ (d & 7);                                  \
            const short* src = vtb + (size_t)d * 2048 + (kb_) + c8 * 8;              \
            __builtin_amdgcn_global_load_lds(AS1(src),                               \
                AS3(&Vs[buf][(w * 64 + i * 256) * 8]), 16, 0, 0);                    \
        }                                                                            \
    }

    STAGE(0, 0);
    __syncthreads();
    int cur = 0;

    for (int t = 0; t < ntiles; ++t) {
        const int kb = t * 64;
        if (t + 1 < ntiles) STAGE(cur ^ 1, kb + 64);

        // ---- QK^T: S[mi][q=grp*4+r][key=kg*16+lo16], K-frag shared across mi
        f32x4 sg[2][4];
        __builtin_amdgcn_s_setprio(1);
#pragma unroll
        for (int kg = 0; kg < 4; ++kg) {
            f32x4 a0 = {}, a1 = {};
#pragma unroll
            for (int ss = 0; ss < 4; ++ss) {
                short8 kf = *reinterpret_cast<const short8*>(
                    &Ks[cur][(kg * 16 + lo16) * 128 + (((ss * 4 + grp) ^ (lo16 & 7)) << 3)]);
                a0 = __builtin_amdgcn_mfma_f32_16x16x32_bf16(qf[0][ss], kf, a0, 0, 0, 0);
                a1 = __builtin_amdgcn_mfma_f32_16x16x32_bf16(qf[1][ss], kf, a1, 0, 0, 0);
            }
            sg[0][kg] = a0; sg[1][kg] = a1;
        }
        __builtin_amdgcn_s_setprio(0);

        // ---- scale (log2 domain) + causal mask (only near diagonal)
        if (kb + 63 > qrow0) {
#pragma unroll
            for (int mi = 0; mi < 2; ++mi)
#pragma unroll
                for (int kg = 0; kg < 4; ++kg) {
                    const int key = kb + kg * 16 + lo16;
#pragma unroll
                    for (int r = 0; r < 4; ++r) {
                        float v = sg[mi][kg][r] * scl2;
                        sg[mi][kg][r] = (key <= qrow0 + mi * 16 + grp * 4 + r) ? v : -1e30f;
                    }
                }
        } else {
#pragma unroll
            for (int mi = 0; mi < 2; ++mi)
#pragma unroll
                for (int kg = 0; kg < 4; ++kg)
#pragma unroll
                    for (int r = 0; r < 4; ++r) sg[mi][kg][r] *= scl2;
        }

        // ---- row max over 64 keys: 4-way local + 16-lane butterfly
        float pm[8];
#pragma unroll
        for (int mi = 0; mi < 2; ++mi)
#pragma unroll
            for (int r = 0; r < 4; ++r)
                pm[mi * 4 + r] = fmaxf(fmaxf(sg[mi][0][r], sg[mi][1][r]),
                                       fmaxf(sg[mi][2][r], sg[mi][3][r]));
#pragma unroll
        for (int off = 1; off < 16; off <<= 1)
#pragma unroll
            for (int i = 0; i < 8; ++i) pm[i] = fmaxf(pm[i], __shfl_xor(pm[i], off));

        // ---- defer-max: rescale only when max grew materially (log2 dom, THR=11.5)
        bool ok = true;
#pragma unroll
        for (int i = 0; i < 8; ++i) ok = ok && (pm[i] <= m[i] + 11.5f);
        if (!__all(ok)) {
            float c[8];
#pragma unroll
            for (int i = 0; i < 8; ++i) {
                float mn = fmaxf(m[i], pm[i]);
                c[i] = __builtin_amdgcn_exp2f(m[i] - mn);
                m[i] = mn;
            }
#pragma unroll
            for (int mi = 0; mi < 2; ++mi) {
#pragma unroll
                for (int jj = 0; jj < 8; ++jj)
#pragma unroll
                    for (int r = 0; r < 4; ++r) o[mi][jj][r] *= c[mi * 4 + r];
#pragma unroll
                for (int r = 0; r < 4; ++r) lac[mi][r] *= c[mi * 4 + r];
            }
        }

        // ---- per-mi: exp2 + P store (16 rows), then PV + row-sum for that mi.
        // Same-wave DS ops are in-order: mi=1 stores can't pass mi=0 reads.
        __builtin_amdgcn_s_setprio(1);
#pragma unroll
        for (int mi = 0; mi < 2; ++mi) {
#pragma unroll
            for (int kg = 0; kg < 4; ++kg)
#pragma unroll
                for (int r = 0; r < 4; ++r) {
                    float p = __builtin_amdgcn_exp2f(sg[mi][kg][r] - m[mi * 4 + r]);
                    int row = grp * 4 + r;
                    int idx = row * 64 + (((kg * 2 + (lo16 >> 3)) ^ (row & 7)) << 3) + (lo16 & 7);
                    pw[idx] = bf_bits(p);
                }
#pragma unroll
            for (int ks = 0; ks < 2; ++ks) {
                short8 pf = *reinterpret_cast<const short8*>(
                    &pw[lo16 * 64 + (((ks * 4 + grp) ^ (lo16 & 7)) << 3)]);
                lac[mi] = __builtin_amdgcn_mfma_f32_16x16x32_bf16(pf, ones, lac[mi], 0, 0, 0);
#pragma unroll
                for (int jj = 0; jj < 8; ++jj) {
                    short8 vf = *reinterpret_cast<const short8*>(
                        &Vs[cur][(jj * 16 + lo16) * 64 + (((ks * 4 + grp) ^ (lo16 & 7)) << 3)]);
                    o[mi][jj] = __builtin_amdgcn_mfma_f32_16x16x32_bf16(pf, vf, o[mi][jj], 0, 0, 0);
                }
            }
        }
        __builtin_amdgcn_s_setprio(0);

        __syncthreads();   // stage writes drained + all reads of cur done
        cur ^= 1;
    }
#undef STAGE

#pragma unroll
    for (int mi = 0; mi < 2; ++mi)
#pragma unroll
        for (int r = 0; r < 4; ++r) {
            float inv = 1.0f / lac[mi][r];
#pragma unroll
            for (int jj = 0; jj < 8; ++jj) {
                outO[(size_t)(b * 2048 + qrow0 + mi * 16 + grp * 4 + r) * 2048
                     + h * 128 + jj * 16 + lo16] = __float2bfloat16(o[mi][jj][r] * inv);
            }
        }
}

extern "C" void kernel_launch(void* const* d_in, const int* in_sizes, int n_in,
                              void* d_out, int out_size, void* d_ws, size_t ws_size,
                              hipStream_t stream)
{
    (void)in_sizes; (void)n_in; (void)out_size; (void)ws_size;
    const float* x  = (const float*)d_in[0];
    const float* Wq = (const float*)d_in[1];
    const float* Wk = (const float*)d_in[2];
    const float* Wv = (const float*)d_in[3];
    const float* Wo = (const float*)d_in[4];

    float* out0 = (float*)d_out;                  // [2,2048,2048]
    float* outk = out0 + 8388608;                 // [2,4,2048,128]
    float* outv = out0 + 10485760;                // [2,4,2048,128]

    __hip_bfloat16* wsb    = (__hip_bfloat16*)d_ws;
    __hip_bfloat16* xb     = wsb;                   //  8,388,608  [4096][2048]
    __hip_bfloat16* WqkvT  = xb + 8388608;          //  6,291,456  [3072][2048]
    __hip_bfloat16* WoT    = WqkvT + 6291456;       //  4,194,304  [2048][2048]
    __hip_bfloat16* qkv    = WoT + 4194304;         // 12,582,912  [4096][3072]
    __hip_bfloat16* VT     = qkv + 12582912;        //  2,097,152  [8][128][2048]
    __hip_bfloat16* attn_o = xb;                    // alias: xb dead after QKV GEMM

    convert_x_kernel<<<8192, 256, 0, stream>>>(x, xb);
    transpose_convert_kernel<<<dim3(64, 64), dim3(32, 8), 0, stream>>>(Wq, WqkvT, 2048, 2048);
    transpose_convert_kernel<<<dim3(16, 64), dim3(32, 8), 0, stream>>>(Wk, WqkvT + (size_t)2048 * 2048, 2048, 512);
    transpose_convert_kernel<<<dim3(16, 64), dim3(32, 8), 0, stream>>>(Wv, WqkvT + (size_t)2560 * 2048, 2048, 512);
    transpose_convert_kernel<<<dim3(64, 64), dim3(32, 8), 0, stream>>>(Wo, WoT, 2048, 2048);

    gemm_bt_kernel<__hip_bfloat16><<<dim3(24, 32), 256, 0, stream>>>(xb, WqkvT, qkv, 4096, 3072, 2048);

    rope_qk_kernel<<<20480, 256, 0, stream>>>(qkv, outk);
    v_writeout_kernel<<<8192, 256, 0, stream>>>(qkv, outv, VT);

    attn_kernel<<<dim3(32, 16), 256, 0, stream>>>(qkv, VT, attn_o);

    gemm_bt_kernel<float><<<dim3(16, 32), 256, 0, stream>>>(attn_o, WoT, out0, 4096, 2048, 2048);
}